// Round 1
// baseline (1408.580 us; speedup 1.0000x reference)
//
#include <hip/hip_runtime.h>
#include <math.h>

#define M 16
#define N 32

// ---------------------------------------------------------------------------
// Representation: X[i,j] is a permutation matrix; perm[i*16+j][a] = column of
// the 1 in row a.  Product X[i,k]@X[k,j] has perm q(b) = p_kj[p_ik[b]].
// vec(X^T) support = { p(b)*32 + b }.  Quadratic form vX^T K vX =
//   sum_{b1,b2} K[i,j][p(b1)*32+b1][p(b2)*32+b2]   (1024 gathered floats).
// ---------------------------------------------------------------------------

__global__ __launch_bounds__(32) void kinit(const float* __restrict__ X,
                                            int* __restrict__ bufA,
                                            int* __restrict__ bufB) {
    int blk = blockIdx.x;          // i*16+j
    int a = threadIdx.x;           // row
    const float* row = X + ((size_t)blk * N + a) * N;
    int p = 0;
    #pragma unroll
    for (int b = 0; b < N; b++) if (row[b] > 0.5f) p = b;
    bufA[blk * N + a] = p;
    bufB[blk * N + a] = p;
}

// Per (i,j): raw_aff (quadform of current perm, 0 on diag) and pair_con.
__global__ __launch_bounds__(256) void k_stats(const float* __restrict__ Kmat,
                                               const int* __restrict__ src,
                                               double* __restrict__ raw_aff,
                                               double* __restrict__ pair_con) {
    int blk = blockIdx.x; int i = blk >> 4, j = blk & 15;
    int t = threadIdx.x;
    __shared__ int pik[M][N];      // perm[i][k]
    __shared__ int pkj[M][N];      // perm[k][j]
    __shared__ int rowoff[N];      // (p(b)*32+b)*1024
    __shared__ int coloff[N];      // p(b)*32+b
    __shared__ int diffs;
    __shared__ double wacc[4];
    #pragma unroll
    for (int u = 0; u < 2; u++) {
        int idx = u * 256 + t; int k = idx >> 5, b = idx & 31;
        pik[k][b] = src[(i * M + k) * N + b];
        pkj[k][b] = src[(k * M + j) * N + b];
    }
    if (t == 0) diffs = 0;
    __syncthreads();
    if (t < 32) { int p = pik[j][t]; rowoff[t] = (p * N + t) << 10; coloff[t] = p * N + t; }
    int cnt = 0;
    #pragma unroll
    for (int u = 0; u < 2; u++) {   // 16 k * 32 b = 512 items
        int idx = u * 256 + t; int k = idx >> 5, b = idx & 31;
        int q = pkj[k][pik[k][b]];          // product perm
        cnt += (q != pik[j][b]);
    }
    atomicAdd(&diffs, cnt);
    __syncthreads();                 // rowoff/coloff ready, diffs final
    double acc = 0.0;
    if (i != j) {
        const float* Kij = Kmat + ((size_t)blk << 20);
        #pragma unroll
        for (int u = 0; u < 4; u++) {
            int idx = u * 256 + t; int b1 = idx >> 5, b2 = idx & 31;
            acc += (double)Kij[rowoff[b1] + coloff[b2]];
        }
    }
    #pragma unroll
    for (int off = 32; off > 0; off >>= 1) acc += __shfl_down(acc, off, 64);
    if ((t & 63) == 0) wacc[t >> 6] = acc;
    __syncthreads();
    if (t == 0) {
        raw_aff[blk]  = (i == j) ? 0.0 : (wacc[0] + wacc[1] + wacc[2] + wacc[3]);
        pair_con[blk] = 1.0 - (double)diffs / 512.0;   // exact
    }
}

// One block per (i<j) pair: 16 waves, wave k scores candidate k, argmax, update.
__global__ __launch_bounds__(1024) void k_update(const float* __restrict__ Kmat,
                                                 const int* __restrict__ src,
                                                 int* __restrict__ dst,
                                                 const double* __restrict__ raw_aff,
                                                 const double* __restrict__ pair_con,
                                                 double constv, int useCon) {
    // map linear block id -> (i,j) with i<j
    int b = blockIdx.x;
    int i = 0; { int r = b; while (r >= M - 1 - i) { r -= M - 1 - i; i++; } b = r; }
    int j = i + 1 + b;
    int t = threadIdx.x;
    int k = t >> 6, l = t & 63;
    __shared__ int qarr[M][N];       // candidate product perms
    __shared__ double red[M];
    __shared__ double score[M];
    __shared__ double norm_s;
    __shared__ int kstar;
    // fill candidate perms; in parallel reduce norm = max(raw_aff)
    if (l < N) {
        int pik = src[(i * M + k) * N + l];
        qarr[k][l] = src[(k * M + j) * N + pik];
    }
    double v = raw_aff[t & 255];
    #pragma unroll
    for (int off = 32; off > 0; off >>= 1) v = fmax(v, __shfl_down(v, off, 64));
    if (l == 0) red[k] = v;
    __syncthreads();
    if (t == 0) {
        double nm = red[0];
        #pragma unroll
        for (int kk = 1; kk < M; kk++) nm = fmax(nm, red[kk]);
        norm_s = nm;
    }
    __syncthreads();
    // quadform for candidate k: lane's column fixed, rows walk 2u+hi
    const float* Kij = Kmat + ((size_t)(i * M + j) << 20);
    int b2 = l & 31, hi = l >> 5;
    int c = qarr[k][b2] * N + b2;
    double acc = 0.0;
    #pragma unroll
    for (int u = 0; u < 16; u++) {
        int b1 = 2 * u + hi;
        int r = qarr[k][b1] * N + b1;
        acc += (double)Kij[(r << 10) + c];
    }
    #pragma unroll
    for (int off = 32; off > 0; off >>= 1) acc += __shfl_down(acc, off, 64);
    if (l == 0) {
        double aff = acc / norm_s;
        double sc = aff;
        if (useCon)
            sc = aff * (1.0 - constv) + sqrt(pair_con[i * M + k] * pair_con[k * M + j]) * constv;
        score[k] = sc;
    }
    __syncthreads();
    if (t == 0) {                    // first-occurrence argmax (matches jnp)
        int ks = 0; double best = score[0];
        for (int kk = 1; kk < M; kk++) if (score[kk] > best) { best = score[kk]; ks = kk; }
        kstar = ks;
    }
    __syncthreads();
    if (t < N) {
        int q = qarr[kstar][t];
        dst[(i * M + j) * N + t] = q;      // upper: new perm
        dst[(j * M + i) * N + q] = t;      // lower: inverse perm
    }
}

__global__ __launch_bounds__(1024) void kout(const int* __restrict__ perm,
                                             float* __restrict__ out) {
    int blk = blockIdx.x; int t = threadIdx.x;
    int a = t >> 5, b = t & 31;
    out[(size_t)blk * 1024 + t] = (perm[blk * N + a] == b) ? 1.0f : 0.0f;
}

extern "C" void kernel_launch(void* const* d_in, const int* in_sizes, int n_in,
                              void* d_out, int out_size, void* d_ws, size_t ws_size,
                              hipStream_t stream) {
    const float* K = (const float*)d_in[0];
    const float* X = (const float*)d_in[1];
    float* out = (float*)d_out;
    char* ws = (char*)d_ws;
    int* bufA = (int*)ws;                       // 16*16*32 int  = 32 KiB
    int* bufB = (int*)(ws + 32768);             // 32 KiB
    double* raw = (double*)(ws + 65536);        // 256 doubles
    double* pc  = (double*)(ws + 65536 + 2048); // 256 doubles

    kinit<<<256, 32, 0, stream>>>(X, bufA, bufB);

    double c = 0.3;
    int cur = 0;
    for (int it = 0; it < 6; ++it) {
        int useCon = (it >= 2);
        if (useCon) c = fmin(c * 1.1, 1.0);     // replicate Python const schedule
        const int* src = cur ? bufB : bufA;
        int* dst = cur ? bufA : bufB;
        k_stats<<<256, 256, 0, stream>>>(K, src, raw, pc);
        k_update<<<120, 1024, 0, stream>>>(K, src, dst, raw, pc, c, useCon);
        cur ^= 1;
    }
    // 6 iterations -> final perms back in bufA
    kout<<<256, 1024, 0, stream>>>(bufA, out);
}